// Round 5
// baseline (332.892 us; speedup 1.0000x reference)
//
#include <hip/hip_runtime.h>
#include <stdint.h>

typedef unsigned short u16;
typedef __bf16 bf16x8 __attribute__((ext_vector_type(8)));
typedef float f32x4 __attribute__((ext_vector_type(4)));

// E=8, D=512, H=256, T=64, B=16384
// LDS map (u16 indices): A [0,8192) = 128r x 64k ; B [8192,40960) = 4e x 128h x 64k
// epilogue reuse: comb [0,17408) = 128 x 136 ; flag @18432 ; gate f32 [20480,22528)
#define GATE_OFF 20480

__device__ __forceinline__ u16 f2bf(float f) {
  unsigned int u = __builtin_bit_cast(unsigned int, f);
  u += 0x7fffu + ((u >> 16) & 1u);  // RNE (finite inputs)
  return (u16)(u >> 16);
}
__device__ __forceinline__ unsigned pk2(float lo, float hi) {
  return (unsigned)f2bf(lo) | ((unsigned)f2bf(hi) << 16);
}
__device__ __forceinline__ uint4 cvt8(float4 a, float4 b) {
  uint4 o;
  o.x = pk2(a.x, a.y);
  o.y = pk2(a.z, a.w);
  o.z = pk2(b.x, b.y);
  o.w = pk2(b.z, b.w);
  return o;
}
__device__ __forceinline__ float bf2f(u16 u) {
  return __builtin_bit_cast(float, ((unsigned)u) << 16);
}

// grid 512: mb = bx&127 (A-sharing blocks -> same XCD), sub = bx>>7 = (ep<<1)|hb.
// 512 thr = 8 waves: wm = wid>>2 (64-row half), wn = wid&3 (32-col slice of 128-h half).
// Per kc(64): stage A+B f32->bf16->LDS (swizzled, 2-way-free), 2 barriers.
// acc[4 experts][4 mt][2 nt] 16x16x32 frags. Gate logits via MFMA on wn==0 waves.
// Epilogue: softmax -> gate LDS -> comb bf16 LDS -> tower MFMA -> bf16 part slice
// -> threadfence + atomic counter; last of 4 blocks finishes sigmoid -> d_out.
__global__ __launch_bounds__(512, 2) void moe_fused(
    const float* __restrict__ xv, const float* __restrict__ We,
    const float* __restrict__ be, const float* __restrict__ Wg,
    const float* __restrict__ bg, const float* __restrict__ Wt,
    const float* __restrict__ bt, u16* __restrict__ part,
    unsigned* __restrict__ counters, float* __restrict__ out) {
  __shared__ u16 lds[40960];  // 80 KB -> 2 blocks/CU

  const int bx = blockIdx.x;
  const int mb = bx & 127, sub = bx >> 7;
  const int ep = sub >> 1, hb = sub & 1;
  const int m0 = mb << 7, h0 = hb << 7, eg0 = ep << 2;
  const int tid = threadIdx.x, lane = tid & 63, wid = tid >> 6;
  const int wm = wid >> 2, wn = wid & 3;
  const int l15 = lane & 15, l4 = lane >> 4;

  f32x4 acc[4][4][2];
#pragma unroll
  for (int e = 0; e < 4; e++)
#pragma unroll
    for (int mt = 0; mt < 4; mt++)
#pragma unroll
      for (int nt = 0; nt < 2; nt++) acc[e][mt][nt] = {0.f, 0.f, 0.f, 0.f};
  f32x4 gacc[4];
#pragma unroll
  for (int mt = 0; mt < 4; mt++) gacc[mt] = {0.f, 0.f, 0.f, 0.f};

  for (int kc = 0; kc < 8; kc++) {
    const int kofs = kc << 6;
    __syncthreads();
    // ---- stage B: 4 experts x 128 h x 64 k (We f32 -> bf16), swizzled ----
#pragma unroll
    for (int r = 0; r < 8; r++) {
      int gbi = r * 512 + tid;
      int el = gbi >> 10, rem = gbi & 1023, n = rem >> 3, g = rem & 7;
      const float* src = We + ((eg0 + el) << 17) + ((h0 + n) << 9) + kofs + (g << 3);
      float4 a = *(const float4*)src;
      float4 b = *(const float4*)(src + 4);
      int slot = g ^ (n & 7);
      *(uint4*)&lds[8192 + (el << 13) + (n << 6) + (slot << 3)] = cvt8(a, b);
    }
    // ---- stage A: 128 rows x 64 k (xv f32 -> bf16), swizzled ----
#pragma unroll
    for (int r = 0; r < 2; r++) {
      int agi = r * 512 + tid;
      int m = agi >> 3, g = agi & 7;
      const float* src = xv + (((m0 + m) << 9) + kofs + (g << 3));
      float4 a = *(const float4*)src;
      float4 b = *(const float4*)(src + 4);
      int slot = g ^ (m & 7);
      *(uint4*)&lds[(m << 6) + (slot << 3)] = cvt8(a, b);
    }
    // ---- gate Wg fragments (wn==0 waves), from global f32 ----
    bf16x8 wgf[2];
    if (wn == 0) {
#pragma unroll
      for (int ks = 0; ks < 2; ks++) {
        const float* src = Wg + ((l15 & 7) << 9) + kofs + ks * 32 + (l4 << 3);
        float4 a = *(const float4*)src;
        float4 b = *(const float4*)(src + 4);
        wgf[ks] = __builtin_bit_cast(bf16x8, cvt8(a, b));
      }
    }
    __syncthreads();
    // ---- compute ----
    bf16x8 af[4][2];
#pragma unroll
    for (int mt = 0; mt < 4; mt++)
#pragma unroll
      for (int ks = 0; ks < 2; ks++) {
        int row = wm * 64 + mt * 16 + l15;
        int gg = ks * 4 + l4;
        int slot = gg ^ (row & 7);
        af[mt][ks] = *(const bf16x8*)&lds[(row << 6) + (slot << 3)];
      }
    if (wn == 0) {
#pragma unroll
      for (int ks = 0; ks < 2; ks++)
#pragma unroll
        for (int mt = 0; mt < 4; mt++)
          gacc[mt] = __builtin_amdgcn_mfma_f32_16x16x32_bf16(
              af[mt][ks], wgf[ks], gacc[mt], 0, 0, 0);
    }
#pragma unroll
    for (int el = 0; el < 4; el++)
#pragma unroll
      for (int ks = 0; ks < 2; ks++) {
        bf16x8 bfr[2];
#pragma unroll
        for (int nt = 0; nt < 2; nt++) {
          int n = wn * 32 + nt * 16 + l15;
          int gg = ks * 4 + l4;
          int slot = gg ^ (n & 7);
          bfr[nt] = *(const bf16x8*)&lds[8192 + (el << 13) + (n << 6) + (slot << 3)];
        }
#pragma unroll
        for (int mt = 0; mt < 4; mt++)
#pragma unroll
          for (int nt = 0; nt < 2; nt++)
            acc[el][mt][nt] = __builtin_amdgcn_mfma_f32_16x16x32_bf16(
                af[mt][ks], bfr[nt], acc[el][mt][nt], 0, 0, 0);
      }
  }

  // ---- gate softmax (wn==0 waves), masked to 8 lanes ----
  __syncthreads();
  float* gateL = (float*)&lds[GATE_OFF];
  if (wn == 0) {
    float bgv = bg[l15 & 7];
#pragma unroll
    for (int mt = 0; mt < 4; mt++) {
#pragma unroll
      for (int i = 0; i < 4; i++) {
        float v = gacc[mt][i] + bgv;
        float mx = fmaxf(v, __shfl_xor(v, 1));
        mx = fmaxf(mx, __shfl_xor(mx, 2));
        mx = fmaxf(mx, __shfl_xor(mx, 4));
        float p = __expf(v - mx);
        float s = p + __shfl_xor(p, 1);
        s += __shfl_xor(s, 2);
        s += __shfl_xor(s, 4);
        if (l15 < 8) {
          int row = wm * 64 + mt * 16 + l4 * 4 + i;
          gateL[row * 8 + l15] = p / s;
        }
      }
    }
  }
  __syncthreads();

  // ---- epilogue: comb = sum_e gate * relu(acc + be) -> comb bf16 in LDS ----
  float bev[4][2];
#pragma unroll
  for (int e = 0; e < 4; e++)
#pragma unroll
    for (int nt = 0; nt < 2; nt++)
      bev[e][nt] = be[(eg0 + e) * 256 + h0 + wn * 32 + nt * 16 + l15];

#pragma unroll
  for (int mt = 0; mt < 4; mt++) {
#pragma unroll
    for (int i = 0; i < 4; i++) {
      int row = wm * 64 + mt * 16 + l4 * 4 + i;
      float4 g4 = *(const float4*)&gateL[row * 8 + eg0];
      const float* gv = &g4.x;
#pragma unroll
      for (int nt = 0; nt < 2; nt++) {
        float c = 0.f;
#pragma unroll
        for (int e = 0; e < 4; e++)
          c += gv[e] * fmaxf(acc[e][mt][nt][i] + bev[e][nt], 0.f);
        lds[row * 136 + wn * 32 + nt * 16 + l15] = f2bf(c);
      }
    }
  }
  __syncthreads();

  // ---- tower partial: [128 rows] x [64 t] over this block's 128 h ----
  f32x4 tacc[4];
#pragma unroll
  for (int ntt = 0; ntt < 4; ntt++) tacc[ntt] = {0.f, 0.f, 0.f, 0.f};
  const int trow = wid * 16 + l15;
#pragma unroll
  for (int ks = 0; ks < 4; ks++) {
    bf16x8 aT = *(const bf16x8*)&lds[trow * 136 + ks * 32 + (l4 << 3)];
#pragma unroll
    for (int ntt = 0; ntt < 4; ntt++) {
      const float* wsrc = Wt + (ntt * 16 + l15) * 256 + h0 + ks * 32 + (l4 << 3);
      float4 a = *(const float4*)wsrc;
      float4 b = *(const float4*)(wsrc + 4);
      bf16x8 bT = __builtin_bit_cast(bf16x8, cvt8(a, b));
      tacc[ntt] = __builtin_amdgcn_mfma_f32_16x16x32_bf16(aT, bT, tacc[ntt], 0, 0, 0);
    }
  }
  u16* pout = part + (((mb << 2) + sub) << 13);  // [mb][sub][128][64]
#pragma unroll
  for (int ntt = 0; ntt < 4; ntt++)
#pragma unroll
    for (int i = 0; i < 4; i++) {
      int grow = wid * 16 + l4 * 4 + i;
      pout[grow * 64 + ntt * 16 + l15] = f2bf(tacc[ntt][i]);
    }

  // ---- last-block-of-4 finish: sigmoid(sum of slices + bt) -> out ----
  __threadfence();
  __syncthreads();
  unsigned* flag = (unsigned*)&lds[18432];
  if (tid == 0) *flag = atomicAdd(&counters[mb], 1u);
  __syncthreads();
  if (*flag == 3u) {
    __threadfence();
    const u16* pbase = part + ((size_t)mb << 15);
    const int ebase = tid * 16;
    const int row = ebase >> 6, col0 = ebase & 63;
    float a[16];
#pragma unroll
    for (int j = 0; j < 16; j++) a[j] = 0.f;
#pragma unroll
    for (int s = 0; s < 4; s++) {
      const u16* ps = pbase + s * 8192 + ebase;
      uint4 p0 = *(const uint4*)ps;
      uint4 p1 = *(const uint4*)(ps + 8);
      unsigned w[8] = {p0.x, p0.y, p0.z, p0.w, p1.x, p1.y, p1.z, p1.w};
#pragma unroll
      for (int j = 0; j < 8; j++) {
        a[2 * j] += bf2f((u16)w[j]);
        a[2 * j + 1] += bf2f((u16)(w[j] >> 16));
      }
    }
#pragma unroll
    for (int j = 0; j < 16; j++) {
      float x = a[j] + bt[col0 + j];
      a[j] = 1.f / (1.f + __expf(-x));
    }
    float* dst = out + (m0 + row) * 64 + col0;
#pragma unroll
    for (int j = 0; j < 4; j++)
      *(float4*)(dst + 4 * j) = make_float4(a[4 * j], a[4 * j + 1], a[4 * j + 2], a[4 * j + 3]);
  }
}

extern "C" void kernel_launch(void* const* d_in, const int* in_sizes, int n_in,
                              void* d_out, int out_size, void* d_ws, size_t ws_size,
                              hipStream_t stream) {
  const float* xv = (const float*)d_in[0];
  const float* We = (const float*)d_in[1];
  const float* be = (const float*)d_in[2];
  const float* Wg = (const float*)d_in[3];
  const float* bg = (const float*)d_in[4];
  const float* Wt = (const float*)d_in[5];
  const float* bt = (const float*)d_in[6];

  char* ws = (char*)d_ws;
  unsigned* counters = (unsigned*)ws;        // 128 x u32 (512 B)
  u16* part = (u16*)(ws + 1024);             // 128 mb x 4 sub x 128 x 64 bf16 = 8 MB

  (void)hipMemsetAsync(counters, 0, 512, stream);
  moe_fused<<<512, 512, 0, stream>>>(xv, We, be, Wg, bg, Wt, bt, part, counters,
                                     (float*)d_out);
}